// Round 3
// baseline (369.449 us; speedup 1.0000x reference)
//
#include <hip/hip_runtime.h>

// Problem: B=4, S=256, V=50257, D=768.
// out[b,s,:] = weight[argmax(one_hot[b,s,:]), :] -- one_hot has exactly one
// nonzero (1.0f) per row, so this is scan-for-nonzero + row gather.
#define VOCAB 50257
#define DIM   768

constexpr int ROWS   = 1024;           // B*S
constexpr int DIM4   = DIM / 4;        // 192 float4 per row
constexpr int TOTAL4 = 12865792;       // ROWS*VOCAB/4 (exact)
constexpr int BLOCK  = 256;
constexpr int T      = 16;             // float4 loads per thread
constexpr int F4_PER_BLOCK = BLOCK * T;                 // 4096
constexpr int FULL_BLOCKS  = TOTAL4 / F4_PER_BLOCK;     // 3141
// tail = TOTAL4 - FULL_BLOCKS*F4_PER_BLOCK = 256 float4s -> 1 extra block

__device__ __forceinline__ void emit_row(long flat, const float4* __restrict__ weight,
                                         float4* __restrict__ out) {
    int row = (int)(flat / VOCAB);
    int col = (int)(flat - (long)row * VOCAB);
    const float4* __restrict__ src = weight + (long)col * DIM4;
    float4* __restrict__ dst = out + (long)row * DIM4;
    #pragma unroll 4
    for (int d = 0; d < DIM4; ++d) dst[d] = src[d];   // 3 KB, L3-hot, pipelined
}

// Fused scan + gather. Main blocks: unchecked 16x block-strided uint4 loads
// (each iteration reads a contiguous 4 KB slab per block -> fully coalesced),
// OR-reduced. Hit threads (1024 total machine-wide) relocate the nonzero and
// copy the weight row directly to out.
__global__ __launch_bounds__(BLOCK) void scan_gather_kernel(
    const uint4* __restrict__ oh, const float4* __restrict__ weight,
    float4* __restrict__ out) {
    const int b = blockIdx.x;

    if (b < FULL_BLOCKS) {
        const int base = b * F4_PER_BLOCK + threadIdx.x;
        unsigned acc = 0;
        #pragma unroll
        for (int k = 0; k < T; ++k) {
            uint4 t = oh[base + k * BLOCK];            // no bounds check
            acc |= t.x | t.y | t.z | t.w;
        }
        if (acc != 0) {
            // Rare path (~1024 threads machine-wide): relocate + gather.
            #pragma unroll 1
            for (int k = 0; k < T; ++k) {
                int i = base + k * BLOCK;
                uint4 t = oh[i];                       // L1/L2-hot reload
                unsigned a[4] = {t.x, t.y, t.z, t.w};
                #pragma unroll
                for (int j = 0; j < 4; ++j)
                    if (a[j] != 0u) emit_row((long)i * 4 + j, weight, out);
            }
        }
    } else {
        // Tail: last 256 float4s, one per thread.
        int i = FULL_BLOCKS * F4_PER_BLOCK + threadIdx.x;
        uint4 t = oh[i];
        unsigned a[4] = {t.x, t.y, t.z, t.w};
        #pragma unroll
        for (int j = 0; j < 4; ++j)
            if (a[j] != 0u) emit_row((long)i * 4 + j, weight, out);
    }
}

extern "C" void kernel_launch(void* const* d_in, const int* in_sizes, int n_in,
                              void* d_out, int out_size, void* d_ws, size_t ws_size,
                              hipStream_t stream) {
    const uint4*  one_hot = (const uint4*)d_in[0];    // [B,S,V] f32 (raw bits)
    const float4* weight  = (const float4*)d_in[1];   // [V,D]  f32
    float4* out = (float4*)d_out;                     // [B,S,D] f32
    (void)d_ws; (void)ws_size;

    scan_gather_kernel<<<FULL_BLOCKS + 1, BLOCK, 0, stream>>>(one_hot, weight, out);
}

// Round 4
// 349.352 us; speedup vs baseline: 1.0575x; 1.0575x over previous
//
#include <hip/hip_runtime.h>

// Problem: B=4, S=256, V=50257, D=768.
// out[b,s,:] = weight[nonzero(one_hot[b,s,:]), :] -- exactly one nonzero per
// row. => scan 206 MB for the 1024 nonzeros, then gather 1024 weight rows.
#define VOCAB 50257
#define DIM   768

constexpr int ROWS   = 1024;            // B*S
constexpr int DIM4   = DIM / 4;         // 192 float4 per weight row
constexpr int TOTAL4 = 12865792;        // ROWS*VOCAB/4 exact (fits int32)

constexpr int BLOCK  = 256;
constexpr int GRID   = 2048;            // 8 blocks/CU on 256 CUs
constexpr int STRIDE = GRID * BLOCK;    // 524288 float4s per grid sweep
constexpr int FULL_ITERS = TOTAL4 / STRIDE;  // 24 unchecked iterations
// remainder: TOTAL4 - 24*STRIDE = 282880 -> one checked tail iteration

// Scan: grid-stride, every iteration is a fully-coalesced machine-wide sweep.
// Hot loop is pure global_load_dwordx4 + v_or; hit path (1024 threads
// machine-wide) reloads L2-hot data to locate the column.
__global__ __launch_bounds__(BLOCK, 4) void find_idx_kernel(
    const uint4* __restrict__ oh, int* __restrict__ idx) {
    const int tid = blockIdx.x * BLOCK + threadIdx.x;

    unsigned acc = 0;
    #pragma unroll
    for (int k = 0; k < FULL_ITERS; ++k) {
        uint4 t = oh[tid + k * STRIDE];          // unchecked, coalesced
        acc |= t.x | t.y | t.z | t.w;
    }
    {   // checked tail iteration
        int i = tid + FULL_ITERS * STRIDE;
        if (i < TOTAL4) {
            uint4 t = oh[i];
            acc |= t.x | t.y | t.z | t.w;
        }
    }

    if (acc != 0) {
        // Rare path: relocate the nonzero(s) this thread saw.
        #pragma unroll 1
        for (int k = 0; k <= FULL_ITERS; ++k) {
            int i = tid + k * STRIDE;
            if (i >= TOTAL4) break;
            uint4 t = oh[i];
            unsigned a[4] = {t.x, t.y, t.z, t.w};
            #pragma unroll
            for (int j = 0; j < 4; ++j) {
                if (a[j] != 0u) {
                    long flat = (long)i * 4 + j;
                    int row = (int)(flat / VOCAB);
                    int col = (int)(flat - (long)row * VOCAB);
                    idx[row] = col;              // exactly one writer per row
                }
            }
        }
    }
}

// Gather: one block per output row, 192 threads copy 192 float4s (3 KB).
__global__ __launch_bounds__(DIM4) void gather_kernel(
    const float4* __restrict__ weight, const int* __restrict__ idx,
    float4* __restrict__ out) {
    int row = blockIdx.x;
    int t   = threadIdx.x;               // 0..191
    int src = idx[row];
    out[row * DIM4 + t] = weight[(long)src * DIM4 + t];
}

extern "C" void kernel_launch(void* const* d_in, const int* in_sizes, int n_in,
                              void* d_out, int out_size, void* d_ws, size_t ws_size,
                              hipStream_t stream) {
    const uint4*  one_hot = (const uint4*)d_in[0];   // [B,S,V] f32 (raw bits)
    const float4* weight  = (const float4*)d_in[1];  // [V,D]  f32
    float4* out = (float4*)d_out;                    // [B,S,D] f32
    int* idx = (int*)d_ws;                           // 1024 ints scratch
                                                     // (fully written by scan)
    find_idx_kernel<<<GRID, BLOCK, 0, stream>>>(one_hot, idx);
    gather_kernel<<<ROWS, DIM4, 0, stream>>>(weight, idx, out);
}

// Round 5
// 324.983 us; speedup vs baseline: 1.1368x; 1.0750x over previous
//
#include <hip/hip_runtime.h>

// Problem: B=4, S=256, V=50257, D=768.
// out[b,s,:] = weight[nonzero(one_hot[b,s,:]), :] -- exactly one nonzero
// (1.0f) per row. => scan 206 MB one_hot for 1024 nonzeros, gather 1024 rows.
//
// R1 structure (best measured across R1-R4: 325/342/369/349 us): one float4
// load per thread, maximal wave parallelism (201k waves, 8192 resident at a
// time, each with one 1 KB/wave outstanding load) saturates HBM without any
// software pipelining. The timed window is harness-dominated (~122 us ws
// poison fill + ~115 us input restores); the scan's 206 MB read is the
// information-flow floor (~33 us at 6.3 TB/s).
#define VOCAB 50257
#define DIM   768

constexpr int ROWS   = 1024;            // B*S
constexpr int DIM4   = DIM / 4;         // 192 float4 per weight row
constexpr int TOTAL4 = 12865792;        // ROWS*VOCAB/4 exact (fits int32)
constexpr int BLOCK  = 256;
constexpr int NBLOCKS = (TOTAL4 + BLOCK - 1) / BLOCK;   // 50258

// Kernel 1: scan one_hot (as raw uint4); one vector per thread. The nonzero
// hit path (1024 threads machine-wide) computes row/col and records the index.
__global__ __launch_bounds__(BLOCK) void find_idx_kernel(
    const uint4* __restrict__ oh, int* __restrict__ idx) {
    int i = blockIdx.x * BLOCK + threadIdx.x;
    if (i >= TOTAL4) return;
    uint4 t = oh[i];
    if ((t.x | t.y | t.z | t.w) != 0u) {
        unsigned a[4] = {t.x, t.y, t.z, t.w};
        long base = (long)i * 4;
        #pragma unroll
        for (int j = 0; j < 4; ++j) {
            if (a[j] != 0u) {
                long flat = base + j;
                int row = (int)(flat / VOCAB);
                int col = (int)(flat - (long)row * VOCAB);
                idx[row] = col;          // exactly one writer per row
            }
        }
    }
}

// Kernel 2: gather weight[idx[row]] -> out[row]; 192 threads copy 3 KB.
__global__ __launch_bounds__(DIM4) void gather_kernel(
    const float4* __restrict__ weight, const int* __restrict__ idx,
    float4* __restrict__ out) {
    int row = blockIdx.x;
    int t   = threadIdx.x;               // 0..191
    int src = idx[row];
    out[row * DIM4 + t] = weight[(long)src * DIM4 + t];
}

extern "C" void kernel_launch(void* const* d_in, const int* in_sizes, int n_in,
                              void* d_out, int out_size, void* d_ws, size_t ws_size,
                              hipStream_t stream) {
    const uint4*  one_hot = (const uint4*)d_in[0];   // [B,S,V] f32 (raw bits)
    const float4* weight  = (const float4*)d_in[1];  // [V,D]  f32
    float4* out = (float4*)d_out;                    // [B,S,D] f32
    int* idx = (int*)d_ws;                           // 1024 ints scratch

    find_idx_kernel<<<NBLOCKS, BLOCK, 0, stream>>>(one_hot, idx);
    gather_kernel<<<ROWS, DIM4, 0, stream>>>(weight, idx, out);
}